// Round 5
// baseline (145.427 us; speedup 1.0000x reference)
//
#include <hip/hip_runtime.h>

#define NN   2048
#define EE   65536
#define EDIM 64
#define LL   5

// Kernel 1: dots[e][l] = sum_d edge_attr[e][d] * edge_vector[l][d]
// 4 edges per wave: lane = (e_sub[2b], dgroup[4b]); float4 over d;
// 4 shuffle levels within 16-lane groups.
__global__ __launch_bounds__(256) void dots_kernel(
    const float* __restrict__ edge_attr,
    const float* __restrict__ edge_vector,
    float* __restrict__ dots) {
  const int lane = threadIdx.x & 63;
  const int wib  = threadIdx.x >> 6;   // wave in block: 0..3
  const int dg   = lane & 15;          // d-group: 4 floats each
  const int es   = lane >> 4;          // edge within wave: 0..3
  const int e    = blockIdx.x * 16 + wib * 4 + es;

  const float4 a = *(const float4*)(edge_attr + e * EDIM + dg * 4);
  float d[LL];
#pragma unroll
  for (int l = 0; l < LL; ++l) {
    const float4 ev = *(const float4*)(edge_vector + l * EDIM + dg * 4);
    d[l] = a.x * ev.x + a.y * ev.y + a.z * ev.z + a.w * ev.w;
  }
#pragma unroll
  for (int s = 1; s <= 8; s <<= 1) {
#pragma unroll
    for (int l = 0; l < LL; ++l) d[l] += __shfl_xor(d[l], s, 64);
  }
  if (dg == 0) {
#pragma unroll
    for (int l = 0; l < LL; ++l) dots[e * LL + l] = d[l];
  }
}

// Kernel 2: 4 (i,j) pairs per thread. Gathers use NON-TEMPORAL loads (nt):
// bypass L1 allocation/miss-queue — every gather misses the 32 KB L1 anyway
// (1.25 MB random table), so if the per-CU L1 miss path is the service wall,
// nt removes it; the table is L2-resident per XCD.
__global__ __launch_bounds__(256) void pairs_kernel(
    const int* __restrict__ ept,
    const float* __restrict__ dots,
    float* __restrict__ out) {
  const long t = (long)blockIdx.x * blockDim.x + threadIdx.x;  // 0 .. N*N/4-1

  const int4* p = (const int4*)(ept + t * 20);
  int buf[20];
#pragma unroll
  for (int k = 0; k < 5; ++k) {
    const int4 v = p[k];
    buf[4 * k + 0] = v.x;
    buf[4 * k + 1] = v.y;
    buf[4 * k + 2] = v.z;
    buf[4 * k + 3] = v.w;
  }

  float vals[20];
#pragma unroll
  for (int q = 0; q < 20; ++q) {
    const int id   = buf[q];
    const int safe = (id < 0) ? 0 : id;
    vals[q] = __builtin_nontemporal_load(dots + safe * LL + (q % LL));
  }
  // Keep all 20 results simultaneously live -> one waitcnt batch.
  asm volatile("" : "+v"(vals[0]), "+v"(vals[1]), "+v"(vals[2]), "+v"(vals[3]),
                    "+v"(vals[4]), "+v"(vals[5]), "+v"(vals[6]), "+v"(vals[7]),
                    "+v"(vals[8]), "+v"(vals[9]), "+v"(vals[10]), "+v"(vals[11]),
                    "+v"(vals[12]), "+v"(vals[13]), "+v"(vals[14]), "+v"(vals[15]),
                    "+v"(vals[16]), "+v"(vals[17]), "+v"(vals[18]), "+v"(vals[19]));

  float rr[4];
#pragma unroll
  for (int k = 0; k < 4; ++k) {
    float s = 0.f;
    int cnt = 0;
#pragma unroll
    for (int l = 0; l < LL; ++l) {
      const int m = (buf[k * LL + l] >= 0);
      s   += m ? vals[k * LL + l] : 0.f;
      cnt += m;
    }
    rr[k] = (cnt > 0) ? s / ((float)cnt + 1e-10f) : 0.f;
  }
  *(float4*)(out + t * 4) = make_float4(rr[0], rr[1], rr[2], rr[3]);
}

extern "C" void kernel_launch(void* const* d_in, const int* in_sizes, int n_in,
                              void* d_out, int out_size, void* d_ws, size_t ws_size,
                              hipStream_t stream) {
  // d_in order: x(unused), edge_attr, edge_vector, edge_paths_tensor, edge_paths_length(unused)
  const float* edge_attr   = (const float*)d_in[1];
  const float* edge_vector = (const float*)d_in[2];
  const int*   ept         = (const int*)d_in[3];
  float* out  = (float*)d_out;
  float* dots = (float*)d_ws;  // E * L * 4 = 1.31 MB scratch

  // Kernel 1: 16 edges per block (4 per wave) -> 4096 blocks.
  dots_kernel<<<EE / 16, 256, 0, stream>>>(edge_attr, edge_vector, dots);

  // Kernel 2: N*N/4 threads, 4 pairs per thread.
  const int total_threads = (NN * NN) / 4;  // 1,048,576
  pairs_kernel<<<total_threads / 256, 256, 0, stream>>>(ept, dots, out);
}

// Round 6
// 40.768 us; speedup vs baseline: 3.5672x; 3.5672x over previous
//
#include <hip/hip_runtime.h>

#define NN   2048
#define EE   65536
#define EDIM 64
#define LL   5
#define TPK2 262144   // total threads in pairs_kernel (256 blocks x 1024)

// Kernel 1: dotsT[l][e] = sum_d edge_attr[e][d] * edge_vector[l][d]  (fp16, transposed)
// 4 edges per wave: lane = (e_sub[2b], dgroup[4b]); float4 over d;
// butterfly over 16-lane groups; lanes dg<5 each store one (e,l) value.
__global__ __launch_bounds__(256) void dots_kernel(
    const float* __restrict__ edge_attr,
    const float* __restrict__ edge_vector,
    _Float16* __restrict__ dotsT) {
  const int lane = threadIdx.x & 63;
  const int wib  = threadIdx.x >> 6;   // wave in block: 0..3
  const int dg   = lane & 15;          // d-group: 4 floats each
  const int es   = lane >> 4;          // edge within wave: 0..3
  const int e    = blockIdx.x * 16 + wib * 4 + es;

  const float4 a = *(const float4*)(edge_attr + e * EDIM + dg * 4);
  float d[LL];
#pragma unroll
  for (int l = 0; l < LL; ++l) {
    const float4 ev = *(const float4*)(edge_vector + l * EDIM + dg * 4);
    d[l] = a.x * ev.x + a.y * ev.y + a.z * ev.z + a.w * ev.w;
  }
#pragma unroll
  for (int s = 1; s <= 8; s <<= 1) {
#pragma unroll
    for (int l = 0; l < LL; ++l) d[l] += __shfl_xor(d[l], s, 64);
  }
  if (dg < LL) {
    // static select (no runtime array index -> no scratch)
    const float dv = (dg == 0) ? d[0] : (dg == 1) ? d[1] : (dg == 2) ? d[2]
                   : (dg == 3) ? d[3] : d[4];
    dotsT[dg * EE + e] = (_Float16)dv;
  }
}

// Kernel 2: persistent, 16 pairs/thread, indices in registers.
// 5 passes (one per l); pass l stages plane dotsT[l][.] (exactly 128 KB) into
// LDS, then each thread gathers its 16 slots with that l from LDS:
// ds_read_u16 + cvt + add. Invalid slots read a zeroed sentinel half.
// This removes ~21M random 4B gathers from the TA/L1/L2 path entirely.
__global__ __launch_bounds__(1024) void pairs_kernel(
    const int* __restrict__ ept,
    const _Float16* __restrict__ dotsT,
    float* __restrict__ out) {
  __shared__ __align__(16) unsigned short tab[EE + 8];  // 128 KB + sentinel
  const int tid = blockIdx.x * 1024 + threadIdx.x;      // 0..262143

  // ---- Load 80 indices (4 groups x 5 int4), convert to LDS byte addrs. ----
  int adr[80];          // slot (pair k, l) at adr[k*5+l]; invalid -> EE*2 (sentinel)
  unsigned cp0 = 0u, cp1 = 0u;  // packed 4-bit valid counts for pairs 0..7 / 8..15
#pragma unroll
  for (int g = 0; g < 4; ++g) {
    const size_t gid = (size_t)g * TPK2 + (size_t)tid;  // 4-pair group id
    const int4* p = (const int4*)(ept + gid * 20);
#pragma unroll
    for (int q = 0; q < 5; ++q) {
      const int4 v = p[q];
#pragma unroll
      for (int jj = 0; jj < 4; ++jj) {
        const int si = q * 4 + jj;                 // 0..19 within group
        const int k  = g * 4 + si / 5;             // pair 0..15 (compile-time)
        const int id = (jj == 0) ? v.x : (jj == 1) ? v.y : (jj == 2) ? v.z : v.w;
        adr[g * 20 + si] = (id < 0) ? (EE * 2) : (id * 2);
        const unsigned m = (id >= 0) ? 1u : 0u;
        if (k < 8) cp0 += m << ((k & 7) * 4); else cp1 += m << ((k & 7) * 4);
      }
    }
  }

  float sum[16];
#pragma unroll
  for (int k = 0; k < 16; ++k) sum[k] = 0.f;

  const char* tabb = (const char*)tab;

  // ---- 5 passes: stage plane l, gather slots with that l. ----
#pragma unroll
  for (int l = 0; l < LL; ++l) {
    __syncthreads();  // previous pass's reads done before overwrite
    const float4* src = (const float4*)(dotsT + (size_t)l * EE);
    float4* dst = (float4*)tab;
#pragma unroll
    for (int r = 0; r < 8; ++r)
      dst[r * 1024 + threadIdx.x] = src[r * 1024 + threadIdx.x];
    if (threadIdx.x == 0) tab[EE] = 0;  // fp16 +0.0 sentinel
    __syncthreads();
#pragma unroll
    for (int k = 0; k < 16; ++k)
      sum[k] += (float)*(const _Float16*)(tabb + adr[k * 5 + l]);
  }

  // ---- Finalize: divide by count, coalesced float4 stores. ----
#pragma unroll
  for (int g = 0; g < 4; ++g) {
    const size_t gid = (size_t)g * TPK2 + (size_t)tid;
    float rr[4];
#pragma unroll
    for (int j = 0; j < 4; ++j) {
      const int k = g * 4 + j;
      const unsigned cnt = (((k < 8) ? cp0 : cp1) >> ((k & 7) * 4)) & 15u;
      rr[j] = sum[k] / ((float)cnt + 1e-10f);  // cnt==0 -> sum==0 -> 0
    }
    ((float4*)out)[gid] = make_float4(rr[0], rr[1], rr[2], rr[3]);
  }
}

extern "C" void kernel_launch(void* const* d_in, const int* in_sizes, int n_in,
                              void* d_out, int out_size, void* d_ws, size_t ws_size,
                              hipStream_t stream) {
  // d_in order: x(unused), edge_attr, edge_vector, edge_paths_tensor, edge_paths_length(unused)
  const float* edge_attr   = (const float*)d_in[1];
  const float* edge_vector = (const float*)d_in[2];
  const int*   ept         = (const int*)d_in[3];
  float* out = (float*)d_out;
  _Float16* dotsT = (_Float16*)d_ws;  // L x E fp16 = 640 KB scratch

  dots_kernel<<<EE / 16, 256, 0, stream>>>(edge_attr, edge_vector, dotsT);

  // Persistent gather kernel: 256 WGs x 1024 threads, 1 WG/CU (128 KB LDS).
  pairs_kernel<<<256, 1024, 0, stream>>>(ept, dotsT, out);
}